// Round 15
// baseline (904.256 us; speedup 1.0000x reference)
//
#include <hip/hip_runtime.h>
#include <hip/hip_bf16.h>

#define HDIM 8192
#define FK 15

typedef __attribute__((ext_vector_type(8))) short bf16x8;
typedef __attribute__((ext_vector_type(8))) unsigned short u16x8;
typedef __attribute__((ext_vector_type(4))) float f32x4;

__device__ __forceinline__ void gload_lds16(const void* g, void* l) {
    __builtin_amdgcn_global_load_lds(
        (const __attribute__((address_space(1))) void*)g,
        (__attribute__((address_space(3))) void*)l, 16, 0, 0);
}

__device__ __forceinline__ float b2f(unsigned short s) {
    unsigned u = (unsigned)s << 16;
    float f;
    __builtin_memcpy(&f, &u, 4);
    return f;
}

// ---------------------------------------------------------------------------
// pack weights to bf16 in MFMA b-fragment order
__global__ void k_pack(const float* __restrict__ W, __hip_bfloat16* __restrict__ P,
                       int O, int C, int Cp, int Fk, int mode) {
    int e = blockIdx.x * 256 + threadIdx.x;
    int total = Fk * Cp * O;
    if (e >= total) return;
    int j = e & 7;
    int lane = (e >> 3) & 63;
    int tile = e >> 9;
    int OT = O >> 4;
    int ot = tile % OT, kt = tile / OT;
    int o = ot * 16 + (lane & 15);
    int kk = kt * 32 + (lane >> 4) * 8 + j;
    float v;
    if (mode == 1) {
        int f = kk / Cp, c = kk % Cp;
        v = (c < C) ? W[(size_t)o * C * Fk + (size_t)c * Fk + f] : 0.f;
    } else if (mode == 2) {
        int f = kk >> 5, oo = kk & 31;
        v = W[(size_t)o * 480 + oo * 15 + f];
    } else {
        v = W[(size_t)o * C + kk];
    }
    P[e] = __float2bfloat16(v);
}

// copy 4 el rows into bf16 catT cols 0..3 (z = stream)
__global__ void k_copy_el2(const float* __restrict__ el0, const float* __restrict__ el1,
                           __hip_bfloat16* __restrict__ c0, __hip_bfloat16* __restrict__ c1,
                           int N, int ld) {
    const float* el = blockIdx.z ? el1 : el0;
    __hip_bfloat16* catT = blockIdx.z ? c1 : c0;
    int n = blockIdx.x * 256 + threadIdx.x;
    if (n >= N) return;
#pragma unroll
    for (int j = 0; j < 4; ++j)
        catT[(size_t)n * ld + j] = __float2bfloat16(el[(size_t)j * N + n]);
}

// embed (z = stream): X (32,N) c-major -> bf16 outT[n*ld+coff+o] = lrelu(W@X+b)
__global__ __launch_bounds__(256) void k_embed2(const float* __restrict__ X0,
                                                const float* __restrict__ X1,
                                                const float* __restrict__ W,
                                                const float* __restrict__ b,
                                                __hip_bfloat16* __restrict__ o0,
                                                __hip_bfloat16* __restrict__ o1,
                                                int N, int O, int ld, int coff) {
    const float* X = blockIdx.z ? X1 : X0;
    __hip_bfloat16* outT = blockIdx.z ? o1 : o0;
    __shared__ float Xs[32][65];
    int tid = threadIdx.x;
    int n0 = blockIdx.x * 64;
    for (int e = tid; e < 32 * 64; e += 256) {
        int nn = e & 63, c = e >> 6;
        Xs[c][nn] = X[(size_t)c * N + n0 + nn];
    }
    __syncthreads();
    int ol = tid & 63, nl = tid >> 6;
    for (int o0i = 0; o0i < O; o0i += 64) {
        int o = o0i + ol;
        float wv[32];
#pragma unroll
        for (int c = 0; c < 32; ++c) wv[c] = W[o * 32 + c];
        float bv = b[o];
        for (int nn = nl; nn < 64; nn += 4) {
            float acc = bv;
#pragma unroll
            for (int c = 0; c < 32; ++c) acc += wv[c] * Xs[c][nn];
            acc = acc >= 0.f ? acc : 0.1f * acc;
            outT[(size_t)(n0 + nn) * ld + coff + o] = __float2bfloat16(acc);
        }
    }
}

// fp32 -> bf16 convert
__global__ void k_cvt(const float* __restrict__ in, __hip_bfloat16* __restrict__ out, int n) {
    int i = (blockIdx.x * 256 + threadIdx.x) * 4;
    if (i >= n) return;
    float4 v = *(const float4*)(in + i);
    out[i + 0] = __float2bfloat16(v.x);
    out[i + 1] = __float2bfloat16(v.y);
    out[i + 2] = __float2bfloat16(v.z);
    out[i + 3] = __float2bfloat16(v.w);
}

// ---------------------------------------------------------------------------
// Blur GEMM f5: block = 128h x (O/2), split-K halves, grid (H/128, 2, 4) = 512
// blocks (2 blocks/CU for barrier-drain overlap). 8 waves = OG o-panels x HG
// h-groups, wave = (MR*16)h x 64o. Per step an 8KB A-slice (128 rows x 32ch)
// is staged via one global_load_lds per thread into a 3-slot ring
// (XOR-pre-swizzled source, swizzled ds_read); W direct-to-register depth-3;
// counted s_waitcnt vmcnt(5) + one s_barrier/step. fp32 partials -> hbuf.
struct W4 { bf16x8 r0, r1, r2, r3; };

template<int OG, int HG, int MR>
__global__ __launch_bounds__(512, 4) void k_blur_f5(
    const __hip_bfloat16* __restrict__ A0b, const __hip_bfloat16* __restrict__ A1b,
    const int* __restrict__ n0, const int* __restrict__ n1,
    const __hip_bfloat16* __restrict__ Wb, float* __restrict__ hbuf,
    int Cp, int O, int H) {
    __shared__ short abuf[3 * 4096];     // 3 x 8KB A ring (128 rows x 32ch)
    __shared__ int idx_s[8 * 128];
    int z = blockIdx.z;
    int strm = z >> 1, kh = z & 1;
    const unsigned short* A = (const unsigned short*)(strm ? A1b : A0b);
    const int* nbrs = strm ? n1 : n0;
    int CpT = Cp >> 5, OT = O >> 4;
    int fbeg = kh ? 8 : 0;
    int fcnt = kh ? (FK - 8) : 8;
    int S = fcnt * CpT;
    size_t NO = (size_t)H * O;
    float* outp = hbuf + (size_t)z * NO;
    const unsigned short* Wp = (const unsigned short*)Wb;
    int tid = threadIdx.x, lane = tid & 63, wid = tid >> 6;
    int r16 = lane & 15, g = lane >> 4;
    int og = wid % OG;
    int hg = wid / OG;
    int h0 = blockIdx.x * 128;
    int obase = blockIdx.y * (OG * 64);
    int otb = blockIdx.y * (OG * 4);
    int srow = tid >> 2;                       // staging row 0..127
    int sgseg = (tid & 3) ^ ((tid >> 3) & 3);  // logical seg at stored pos tid&3
    int pseg = g ^ ((r16 >> 1) & 3);           // stored pos of logical seg g
    int hgbase = hg * (MR * 16);
    char* abase = (char*)abuf;

    for (int e = tid; e < fcnt * 128; e += 512)
        idx_s[e] = nbrs[(size_t)(fbeg + (e >> 7)) * H + h0 + (e & 127)];
    __syncthreads();

    f32x4 acc[MR][4];
#pragma unroll
    for (int m = 0; m < MR; ++m)
#pragma unroll
        for (int n = 0; n < 4; ++n) acc[m][n] = (f32x4){0.f, 0.f, 0.f, 0.f};

    W4 wA, wB, wC;
    int tS = 0, cS = 0, fS = 0;

#define STAGE_AW(SLOTA, W)                                                         \
    do {                                                                           \
        int gi = idx_s[fS * 128 + srow];                                           \
        gload_lds16(A + (size_t)gi * Cp + cS * 32 + sgseg * 8,                     \
                    abase + (SLOTA) * 8192 + tid * 16);                            \
        const unsigned short* wbp =                                                \
            Wp + ((size_t)(((fbeg + fS) * CpT + cS) * OT + otb + og * 4)) * 512 + lane * 8; \
        W.r0 = *(const bf16x8*)(wbp);                                              \
        W.r1 = *(const bf16x8*)(wbp + 512);                                        \
        W.r2 = *(const bf16x8*)(wbp + 1024);                                       \
        W.r3 = *(const bf16x8*)(wbp + 1536);                                       \
        if (tS < S - 1) { ++tS; if (++cS == CpT) { cS = 0; ++fS; } }               \
    } while (0)

#define FITER(SLOT, WCUR, WNXT)                                                    \
    do {                                                                           \
        __builtin_amdgcn_sched_barrier(0);                                         \
        asm volatile("s_waitcnt vmcnt(5)" ::: "memory");                           \
        __builtin_amdgcn_sched_barrier(0);                                         \
        __builtin_amdgcn_s_barrier();                                              \
        __builtin_amdgcn_sched_barrier(0);                                         \
        STAGE_AW(((SLOT) + 2) % 3, WNXT);                                          \
        const short* ab = abuf + (SLOT) * 4096;                                    \
        bf16x8 av[MR];                                                             \
        _Pragma("unroll")                                                          \
        for (int rb = 0; rb < MR; ++rb)                                            \
            av[rb] = *(const bf16x8*)(ab + (hgbase + rb * 16 + r16) * 32 + pseg * 8); \
        _Pragma("unroll")                                                          \
        for (int rb = 0; rb < MR; ++rb) {                                          \
            acc[rb][0] = __builtin_amdgcn_mfma_f32_16x16x32_bf16(av[rb], WCUR.r0, acc[rb][0], 0, 0, 0); \
            acc[rb][1] = __builtin_amdgcn_mfma_f32_16x16x32_bf16(av[rb], WCUR.r1, acc[rb][1], 0, 0, 0); \
            acc[rb][2] = __builtin_amdgcn_mfma_f32_16x16x32_bf16(av[rb], WCUR.r2, acc[rb][2], 0, 0, 0); \
            acc[rb][3] = __builtin_amdgcn_mfma_f32_16x16x32_bf16(av[rb], WCUR.r3, acc[rb][3], 0, 0, 0); \
        }                                                                          \
    } while (0)

    STAGE_AW(0, wA);
    STAGE_AW(1, wB);
    for (int t = 0; t < S; t += 3) {
        FITER(0, wA, wC);
        if (t + 1 < S) FITER(1, wB, wA);
        if (t + 2 < S) FITER(2, wC, wB);
    }
#undef FITER
#undef STAGE_AW

#pragma unroll
    for (int n = 0; n < 4; ++n) {
        int o = obase + og * 64 + n * 16 + r16;
#pragma unroll
        for (int m = 0; m < MR; ++m)
#pragma unroll
            for (int i = 0; i < 4; ++i)
                outp[(size_t)(h0 + hgbase + m * 16 + g * 4 + i) * O + o] = acc[m][n][i];
    }
}

// combine split-K halves (z = stream): out = lrelu(p0 + p1 + bias) -> bf16
__global__ void k_comb2(const float* __restrict__ p, const float* __restrict__ bias,
                        __hip_bfloat16* __restrict__ out0, __hip_bfloat16* __restrict__ out1,
                        int NO, int Om) {
    const float* pp = p + (size_t)blockIdx.z * 2 * NO;
    __hip_bfloat16* out = blockIdx.z ? out1 : out0;
    int i = blockIdx.x * 256 + threadIdx.x;
    int stride = gridDim.x * 256;
    for (; i < NO; i += stride) {
        float v = pp[i] + pp[i + NO] + bias[i & Om];
        v = v >= 0.f ? v : 0.1f * v;
        out[i] = __float2bfloat16(v);
    }
}

// ---------------------------------------------------------------------------
// R7 register-pipeline macros (dense bf16 GEMM)
#define DEF_PIPE_VARS                                                              \
    bf16x8 a00, a01, w00, w01, w02, w03;                                           \
    bf16x8 a10, a11, w10, w11, w12, w13;                                           \
    bf16x8 a20, a21, w20, w21, w22, w23;

#define LOADST(J, TEND, FEND)                                                      \
    do {                                                                           \
        const unsigned short* a0p = A + (size_t)i0c * Cp + cL * 32 + g * 8;        \
        const unsigned short* a1p = A + (size_t)i1c * Cp + cL * 32 + g * 8;        \
        a##J##0 = *(const bf16x8*)a0p;                                             \
        a##J##1 = *(const bf16x8*)a1p;                                             \
        const unsigned short* wbp = Wp + ((size_t)(tL * OT + otb)) * 512 + lane * 8; \
        w##J##0 = *(const bf16x8*)(wbp);                                           \
        w##J##1 = *(const bf16x8*)(wbp + 512);                                     \
        w##J##2 = *(const bf16x8*)(wbp + 1024);                                    \
        w##J##3 = *(const bf16x8*)(wbp + 1536);                                    \
        if (tL < (TEND) - 1) {                                                     \
            ++tL;                                                                  \
            if (++cL == CpT) {                                                     \
                cL = 0; ++fL;                                                      \
                i0c = i0n; i1c = i1n;                                              \
                if (fL + 1 < (FEND)) {                                             \
                    i0n = nbrs ? nbrs[(size_t)(fL + 1) * H + hrow] : hrow;         \
                    i1n = nbrs ? nbrs[(size_t)(fL + 1) * H + hrow + 16] : (hrow + 16); \
                }                                                                  \
            }                                                                      \
        }                                                                          \
    } while (0)

#define MFMAST(J)                                                                  \
    do {                                                                           \
        acc[0][0] = __builtin_amdgcn_mfma_f32_16x16x32_bf16(a##J##0, w##J##0, acc[0][0], 0, 0, 0); \
        acc[0][1] = __builtin_amdgcn_mfma_f32_16x16x32_bf16(a##J##0, w##J##1, acc[0][1], 0, 0, 0); \
        acc[0][2] = __builtin_amdgcn_mfma_f32_16x16x32_bf16(a##J##0, w##J##2, acc[0][2], 0, 0, 0); \
        acc[0][3] = __builtin_amdgcn_mfma_f32_16x16x32_bf16(a##J##0, w##J##3, acc[0][3], 0, 0, 0); \
        acc[1][0] = __builtin_amdgcn_mfma_f32_16x16x32_bf16(a##J##1, w##J##0, acc[1][0], 0, 0, 0); \
        acc[1][1] = __builtin_amdgcn_mfma_f32_16x16x32_bf16(a##J##1, w##J##1, acc[1][1], 0, 0, 0); \
        acc[1][2] = __builtin_amdgcn_mfma_f32_16x16x32_bf16(a##J##1, w##J##2, acc[1][2], 0, 0, 0); \
        acc[1][3] = __builtin_amdgcn_mfma_f32_16x16x32_bf16(a##J##1, w##J##3, acc[1][3], 0, 0, 0); \
    } while (0)

// MFMA GEMM (dense bf16 A), 128h x 64o tile, 4 waves.
__global__ __launch_bounds__(256) void k_mfma_gemm(const __hip_bfloat16* __restrict__ Ab,
                                                   const int* __restrict__ nbrs,
                                                   const __hip_bfloat16* __restrict__ Wb,
                                                   const float* __restrict__ bias,
                                                   float* __restrict__ outF,
                                                   __hip_bfloat16* __restrict__ outB,
                                                   int Cp, int Fk, int O, int H, int act,
                                                   const __hip_bfloat16* Ab1,
                                                   float* outF1, __hip_bfloat16* outB1) {
    if (blockIdx.z) { Ab = Ab1; outF = outF1; outB = outB1; }
    const unsigned short* A = (const unsigned short*)Ab;
    const unsigned short* Wp = (const unsigned short*)Wb;
    int tid = threadIdx.x, lane = tid & 63, w = tid >> 6;
    int r16 = lane & 15, g = lane >> 4;
    int h0 = blockIdx.x * 128, o0 = blockIdx.y * 64;
    int OT = O >> 4, CpT = Cp >> 5, S = Fk * CpT;
    int otb = o0 >> 4;
    int w32 = w * 32;
    int hrow = h0 + w32 + r16;

    int i0c = nbrs ? nbrs[hrow] : hrow;
    int i1c = nbrs ? nbrs[hrow + 16] : (hrow + 16);
    int i0n = i0c, i1n = i1c;
    if (Fk > 1) {
        i0n = nbrs[(size_t)H + hrow];
        i1n = nbrs[(size_t)H + hrow + 16];
    }

    f32x4 acc[2][4];
#pragma unroll
    for (int m = 0; m < 2; ++m)
#pragma unroll
        for (int n = 0; n < 4; ++n) acc[m][n] = (f32x4){0.f, 0.f, 0.f, 0.f};

    DEF_PIPE_VARS
    int tL = 0, cL = 0, fL = 0;

    LOADST(0, S, Fk);
    LOADST(1, S, Fk);
    for (int sb = 0; sb < S; sb += 3) {
        LOADST(2, S, Fk);
        MFMAST(0);
        LOADST(0, S, Fk);
        if (sb + 1 < S) MFMAST(1);
        LOADST(1, S, Fk);
        if (sb + 2 < S) MFMAST(2);
    }

#pragma unroll
    for (int n = 0; n < 4; ++n) {
        int o = o0 + n * 16 + r16;
        float bv = bias[o];
#pragma unroll
        for (int m = 0; m < 2; ++m) {
#pragma unroll
            for (int i = 0; i < 4; ++i) {
                int h = h0 + w32 + m * 16 + g * 4 + i;
                float v = acc[m][n][i] + bv;
                if (act) v = v >= 0.f ? v : 0.1f * v;
                if (outF) outF[(size_t)h * O + o] = v;
                if (outB) outB[(size_t)h * O + o] = __float2bfloat16(v);
            }
        }
    }
}

// ---------------------------------------------------------------------------
// slice (bf16 out)
__global__ void k_slice_b(const float* __restrict__ latT, const float* __restrict__ bary,
                          const int* __restrict__ off, __hip_bfloat16* __restrict__ outT,
                          int N, int C, int ld, int coff) {
    int cl = threadIdx.x & 63, rr = threadIdx.x >> 6;
    int n = blockIdx.x * 4 + rr;
    int c = blockIdx.y * 64 + cl;
    float s = 0.f;
#pragma unroll
    for (int j = 0; j < 4; ++j) {
        int o = off[(size_t)j * N + n];
        float w = bary[(size_t)j * N + n];
        s += latT[(size_t)o * C + c] * w;
    }
    outT[(size_t)n * ld + coff + c] = __float2bfloat16(s);
}

// fused slice -> splat (same bary/off pair)
__global__ void k_slice_splat(const float* __restrict__ latT, const float* __restrict__ bary,
                              const int* __restrict__ off, float* __restrict__ dst,
                              int N, int C) {
    int cl = threadIdx.x & 63, rr = threadIdx.x >> 6;
    int n = blockIdx.x * 4 + rr;
    int c = blockIdx.y * 64 + cl;
    int o[4];
    float w[4];
    float s = 0.f;
#pragma unroll
    for (int j = 0; j < 4; ++j) {
        o[j] = off[(size_t)j * N + n];
        w[j] = bary[(size_t)j * N + n];
        s += latT[(size_t)o[j] * C + c] * w[j];
    }
#pragma unroll
    for (int j = 0; j < 4; ++j)
        atomicAdd(&dst[(size_t)o[j] * C + c], s * w[j]);
}

// ---------------------------------------------------------------------------
// MFMA correlation MLP. Block = 64 positions (same f), 4 waves.
// ALL gathered tables bf16 (L1, f2, P1).
__global__ __launch_bounds__(256) void k_corr_mfma(const __hip_bfloat16* __restrict__ L1b,
                                                   const __hip_bfloat16* __restrict__ f2b,
                                                   const __hip_bfloat16* __restrict__ P1b,
                                                   const int* __restrict__ idx1,
                                                   const int* __restrict__ idx2,
                                                   const __hip_bfloat16* __restrict__ W0p,
                                                   const float* __restrict__ b0,
                                                   const __hip_bfloat16* __restrict__ W1p,
                                                   const float* __restrict__ b1,
                                                   __hip_bfloat16* __restrict__ h1T,
                                                   int H, int C1, int C2) {
    __shared__ __hip_bfloat16 As[64 * 72];
    __shared__ __hip_bfloat16 A0s[64 * 40];
    __shared__ int i1s[64], i2s[64];
    const unsigned short* L1u = (const unsigned short*)L1b;
    const unsigned short* f2u = (const unsigned short*)f2b;
    const unsigned short* P1u = (const unsigned short*)P1b;
    int tid = threadIdx.x;
    int p0 = blockIdx.x * 64;
    int f = p0 >> 13;                 // H == 8192
    int h0 = p0 & (HDIM - 1);
    if (tid < 64) {
        i1s[tid] = idx1[(size_t)f * H + h0 + tid];
        i2s[tid] = idx2[(size_t)f * H + h0 + tid];
    }
    __syncthreads();
    int lane = tid & 63, wid = tid >> 6;
    int wh = wid * 16;
    int r16 = lane & 15, g = lane >> 4;
    int srow = tid >> 2, sseg = tid & 3;
    int K = C1 + C2;
    const unsigned short* W0u = (const unsigned short*)W0p;
    const unsigned short* W1u = (const unsigned short*)W1p;
    f32x4 acc[2];
    acc[0] = (f32x4){0.f, 0.f, 0.f, 0.f};
    acc[1] = (f32x4){0.f, 0.f, 0.f, 0.f};

    for (int c0 = 0; c0 < K; c0 += 64) {
        int cb = c0 + sseg * 16;
        float x[16];
        if (cb < C1) {
            u16x8 av0 = *(const u16x8*)(L1u + (size_t)i1s[srow] * C1 + cb);
            u16x8 av1 = *(const u16x8*)(L1u + (size_t)i1s[srow] * C1 + cb + 8);
            u16x8 bv0 = *(const u16x8*)(f2u + (size_t)i2s[srow] * C1 + cb);
            u16x8 bv1 = *(const u16x8*)(f2u + (size_t)i2s[srow] * C1 + cb + 8);
#pragma unroll
            for (int u = 0; u < 8; ++u) {
                x[u]     = b2f(av0[u]) * b2f(bv0[u]);
                x[8 + u] = b2f(av1[u]) * b2f(bv1[u]);
            }
        } else {
            u16x8 p0v = *(const u16x8*)(P1u + (size_t)i1s[srow] * C2 + (cb - C1));
            u16x8 p1v = *(const u16x8*)(P1u + (size_t)i1s[srow] * C2 + (cb - C1) + 8);
#pragma unroll
            for (int u = 0; u < 8; ++u) {
                x[u] = b2f(p0v[u]);
                x[8 + u] = b2f(p1v[u]);
            }
        }
        __syncthreads();
        __hip_bfloat16* dst = &As[srow * 72 + sseg * 16];
#pragma unroll
        for (int q = 0; q < 16; ++q) dst[q] = __float2bfloat16(x[q]);
        __syncthreads();
        int ktg = c0 >> 5;
#pragma unroll
        for (int kt = 0; kt < 2; ++kt) {
            bf16x8 a = *(const bf16x8*)(&As[(wh + r16) * 72 + kt * 32 + g * 8]);
            const unsigned short* wb = W0u + (size_t)((ktg + kt) * 2) * 512 + lane * 8;
            bf16x8 bf0 = *(const bf16x8*)(wb);
            bf16x8 bf1 = *(const bf16x8*)(wb + 512);
            acc[0] = __builtin_amdgcn_mfma_f32_16x16x32_bf16(a, bf0, acc[0], 0, 0, 0);
            acc[1] = __builtin_amdgcn_mfma_f32_16x16x32_bf16(a, bf1, acc[1], 0, 0, 0);
        }
    }
    __syncthreads();
#pragma unroll
    for (int ot = 0; ot < 2; ++ot) {
        int o = ot * 16 + r16;
        float bv = b0[o];
#pragma unroll
        for (int i = 0; i < 4; ++i) {
            int pr = wh + g * 4 + i;
            float v = acc[ot][i] + bv;
            v = v >= 0.f ? v : 0.1f * v;
            A0s[pr * 40 + o] = __float2bfloat16(v);
        }
    }
    __syncthreads();
    bf16x8 a1 = *(const bf16x8*)(&A0s[(wh + r16) * 40 + g * 8]);
    bf16x8 w1f0 = *(const bf16x8*)(W1u + lane * 8);
    bf16x8 w1f1 = *(const bf16x8*)(W1u + 512 + lane * 8);
    f32x4 acc1[2];
    acc1[0] = (f32x4){0.f, 0.f, 0.f, 0.f};
    acc1[1] = (f32x4){0.f, 0.f, 0.f, 0.f};
    acc1[0] = __builtin_amdgcn_mfma_f32_16x16x32_bf16(a1, w1f0, acc1[0], 0, 0, 0);
    acc1[1] = __builtin_amdgcn_mfma_f32_16x16x32_bf16(a1, w1f1, acc1[1], 0, 0, 0);
#pragma unroll
    for (int ot = 0; ot < 2; ++ot) {
        int o = ot * 16 + r16;
        float bv = b1[o];
#pragma unroll
        for (int i = 0; i < 4; ++i) {
            int h = h0 + wh + g * 4 + i;
            float v = acc1[ot][i] + bv;
            v = v >= 0.f ? v : 0.1f * v;
            h1T[(size_t)h * 480 + f * 32 + o] = __float2bfloat16(v);
        }
    }
}

// ---------------------------------------------------------------------------
// final 256 -> 3 head, writes (3, N) c-major
__global__ void k_final(const float* __restrict__ r2T, const float* __restrict__ W,
                        const float* __restrict__ b, float* __restrict__ out, int N) {
    int n = blockIdx.x * 256 + threadIdx.x;
    if (n >= N) return;
    float s0 = b[0], s1 = b[1], s2 = b[2];
    const float4* x4 = (const float4*)(r2T + (size_t)n * 256);
    for (int q = 0; q < 64; ++q) {
        float4 v = x4[q];
        float xs[4] = {v.x, v.y, v.z, v.w};
#pragma unroll
        for (int u = 0; u < 4; ++u) {
            int c = 4 * q + u;
            s0 = fmaf(W[c], xs[u], s0);
            s1 = fmaf(W[256 + c], xs[u], s1);
            s2 = fmaf(W[512 + c], xs[u], s2);
        }
    }
    out[n] = s0;
    out[(size_t)N + n] = s1;
    out[(size_t)2 * N + n] = s2;
}

// ---------------------------------------------------------------------------
extern "C" void kernel_launch(void* const* d_in, const int* in_sizes, int n_in,
                              void* d_out, int out_size, void* d_ws, size_t ws_size,
                              hipStream_t stream) {
    const int N = HDIM;
    auto F32 = [&](int i) { return (const float*)d_in[i]; };
    auto I32 = [&](int i) { return (const int*)d_in[i]; };

    char* base = (char*)d_ws;
    size_t off = 0;
    auto allocB = [&](size_t elems) -> __hip_bfloat16* {
        __hip_bfloat16* r = (__hip_bfloat16*)(base + off);
        off += ((elems * 2 + 255) / 256) * 256;
        return r;
    };
    auto allocF = [&](size_t elems) -> float* {
        float* r = (float*)(base + off);
        off += ((elems * 4 + 255) / 256) * 256;
        return r;
    };

    // packed bf16 weights
    __hip_bfloat16* pw_up2   = allocB((size_t)15 * 160 * 256);
    __hip_bfloat16* pw_up1   = allocB((size_t)15 * 544 * 512);
    __hip_bfloat16* pw_up2_1 = allocB((size_t)256 * 256);
    __hip_bfloat16* pw_up1_1 = allocB((size_t)512 * 512);
    __hip_bfloat16* pw_c2o   = allocB((size_t)480 * 256);
    __hip_bfloat16* pw_c2o1  = allocB((size_t)256 * 256);
    __hip_bfloat16* pw_c1o   = allocB((size_t)480 * 512);
    __hip_bfloat16* pw_c1o1  = allocB((size_t)512 * 512);
    __hip_bfloat16* pw_s4    = allocB((size_t)512 * 512);
    __hip_bfloat16* pw_s2    = allocB((size_t)512 * 256);
    __hip_bfloat16* pw_cc20  = allocB((size_t)256 * 32);
    __hip_bfloat16* pw_cc21  = allocB((size_t)32 * 32);
    __hip_bfloat16* pw_cc10  = allocB((size_t)768 * 32);
    __hip_bfloat16* pw_cc11  = allocB((size_t)32 * 32);
    // bf16 activations
    __hip_bfloat16* catb2a = allocB((size_t)N * 160);
    __hip_bfloat16* catb2b = allocB((size_t)N * 160);
    __hip_bfloat16* catb1a = allocB((size_t)N * 544);
    __hip_bfloat16* catb1b = allocB((size_t)N * 544);
    __hip_bfloat16* ab512a = allocB((size_t)N * 512);
    __hip_bfloat16* ab512b = allocB((size_t)N * 512);
    __hip_bfloat16* ab256a = allocB((size_t)N * 256);
    __hip_bfloat16* ab256b = allocB((size_t)N * 256);
    __hip_bfloat16* h1b    = allocB((size_t)N * 480);
    __hip_bfloat16* corr1b = allocB((size_t)N * 512);
    __hip_bfloat16* SL256b = allocB((size_t)N * 256);
    __hip_bfloat16* SL512b = allocB((size_t)N * 512);
    __hip_bfloat16* SP256b = allocB((size_t)N * 256);
    __hip_bfloat16* pclBb  = allocB((size_t)N * 256);   // corr2 f2 (bf16)
    __hip_bfloat16* pcl11b = allocB((size_t)N * 512);   // corr1 f2 (bf16)
    // fp32 buffers
    float* T512a  = allocF((size_t)N * 512);
    float* T512b  = allocF((size_t)N * 512);
    float* SL512  = allocF((size_t)N * 512);
    float* SL256  = allocF((size_t)N * 256);   // later SP256
    float* hbuf   = allocF((size_t)4 * N * 512);  // split-K partials (4 slabs)
    float* SP256 = SL256;
    (void)ws_size; (void)in_sizes; (void)n_in; (void)out_size;

    // --- weight packing (bf16, MFMA fragment order) ---
    auto pack = [&](const float* W, __hip_bfloat16* P, int O, int C, int Cp, int Fk, int mode) {
        int total = Fk * Cp * O;
        k_pack<<<(total + 255) / 256, 256, 0, stream>>>(W, P, O, C, Cp, Fk, mode);
    };
    pack(F32(32), pw_up2,   256, 132, 160, 15, 1);
    pack(F32(36), pw_up1,   512, 516, 544, 15, 1);
    pack(F32(34), pw_up2_1, 256, 256, 256, 1, 0);
    pack(F32(38), pw_up1_1, 512, 512, 512, 1, 0);
    pack(F32(44), pw_c2o,   256, 480, 480, 1, 2);
    pack(F32(46), pw_c2o1,  256, 256, 256, 1, 0);
    pack(F32(52), pw_c1o,   512, 480, 480, 1, 2);
    pack(F32(54), pw_c1o1,  512, 512, 512, 1, 0);
    pack(F32(56), pw_s4,    512, 512, 512, 1, 0);
    pack(F32(58), pw_s2,    256, 512, 512, 1, 0);
    pack(F32(40), pw_cc20,  32, 256, 256, 1, 0);
    pack(F32(42), pw_cc21,  32, 32, 32, 1, 0);
    pack(F32(48), pw_cc10,  32, 768, 768, 1, 0);
    pack(F32(50), pw_cc11,  32, 32, 32, 1, 0);

    // --- zero-init (pads + splat accumulators) ---
    hipMemsetAsync(catb2a, 0, (size_t)N * 160 * 2, stream);
    hipMemsetAsync(catb2b, 0, (size_t)N * 160 * 2, stream);
    hipMemsetAsync(catb1a, 0, (size_t)N * 544 * 2, stream);
    hipMemsetAsync(catb1b, 0, (size_t)N * 544 * 2, stream);
    hipMemsetAsync(SL256,  0, (size_t)N * 256 * 4, stream);
    hipMemsetAsync(SL512,  0, (size_t)N * 512 * 4, stream);

    // --- Stage A: level-2 embed + blur f5 + comb + conv + slices ---
    k_copy_el2<<<dim3(32, 1, 2), 256, 0, stream>>>(F32(6), F32(7), catb2a, catb2b, N, 160);
    k_embed2<<<dim3(128, 1, 2), 256, 0, stream>>>(F32(1), F32(4), F32(28), F32(29),
                                                  catb2a, catb2b, N, 128, 160, 4);
    k_blur_f5<2, 4, 2><<<dim3(64, 2, 4), 512, 0, stream>>>(catb2a, catb2b, I32(20), I32(21),
                                                           pw_up2, hbuf, 160, 256, N);
    k_comb2<<<dim3(2048, 1, 2), 256, 0, stream>>>(hbuf, F32(33), ab256a, ab256b, N * 256, 255);
    k_mfma_gemm<<<dim3(64, 4, 2), 256, 0, stream>>>(ab256a, nullptr, pw_up2_1, F32(35),
                                                    T512a, nullptr, 256, 1, 256, N, 0,
                                                    ab256b, T512b, nullptr);
    k_slice_b<<<dim3(2048, 4), 256, 0, stream>>>(T512a, F32(12), I32(17), catb1a, N, 256, 544, 4);
    k_slice_b<<<dim3(2048, 4), 256, 0, stream>>>(T512b, F32(11), I32(16), pclBb, N, 256, 256, 0);
    k_slice_b<<<dim3(2048, 4), 256, 0, stream>>>(T512b, F32(13), I32(18), catb1b, N, 256, 544, 4);

    // --- Stage B: corr2 ---
    k_slice_splat<<<dim3(2048, 4), 256, 0, stream>>>(T512a, F32(10), I32(15), SL256, N, 256);
    k_cvt<<<(N * 256 / 4 + 255) / 256, 256, 0, stream>>>(SL256, SL256b, N * 256);
    k_corr_mfma<<<FK * HDIM / 64, 256, 0, stream>>>(SL256b, pclBb, (const __hip_bfloat16*)nullptr,
                                                    I32(24), I32(25), pw_cc20, F32(41),
                                                    pw_cc21, F32(43), h1b, N, 256, 0);
    k_mfma_gemm<<<dim3(64, 4), 256, 0, stream>>>(h1b, nullptr, pw_c2o, F32(45),
                                                 nullptr, ab256a, 480, 1, 256, N, 1,
                                                 nullptr, nullptr, nullptr);
    k_mfma_gemm<<<dim3(64, 4), 256, 0, stream>>>(ab256a, nullptr, pw_c2o1, F32(47),
                                                 T512a, nullptr, 256, 1, 256, N, 0,
                                                 nullptr, nullptr, nullptr);
    hipMemsetAsync(SP256, 0, (size_t)N * 256 * 4, stream);
    k_slice_splat<<<dim3(2048, 4), 256, 0, stream>>>(T512a, F32(12), I32(17), SP256, N, 256);
    k_cvt<<<(N * 256 / 4 + 255) / 256, 256, 0, stream>>>(SP256, SP256b, N * 256);

    // --- Stage C: level-1 embed + blur f5 + comb + conv + slices ---
    k_copy_el2<<<dim3(32, 1, 2), 256, 0, stream>>>(F32(8), F32(9), catb1a, catb1b, N, 544);
    k_embed2<<<dim3(128, 1, 2), 256, 0, stream>>>(F32(0), F32(3), F32(30), F32(31),
                                                  catb1a, catb1b, N, 256, 544, 260);
    k_blur_f5<4, 2, 4><<<dim3(64, 2, 4), 512, 0, stream>>>(catb1a, catb1b, I32(22), I32(23),
                                                           pw_up1, hbuf, 544, 512, N);
    k_comb2<<<dim3(2048, 1, 2), 256, 0, stream>>>(hbuf, F32(37), ab512a, ab512b, N * 512, 511);
    k_mfma_gemm<<<dim3(64, 8, 2), 256, 0, stream>>>(ab512a, nullptr, pw_up1_1, F32(39),
                                                    T512a, nullptr, 512, 1, 512, N, 0,
                                                    ab512b, T512b, nullptr);
    k_slice_b<<<dim3(2048, 8), 256, 0, stream>>>(T512b, F32(13), I32(18), pcl11b, N, 512, 512, 0);

    // --- Stage D: corr1 ---
    k_slice_splat<<<dim3(2048, 8), 256, 0, stream>>>(T512a, F32(12), I32(17), SL512, N, 512);
    k_cvt<<<(N * 512 / 4 + 255) / 256, 256, 0, stream>>>(SL512, SL512b, N * 512);
    k_corr_mfma<<<FK * HDIM / 64, 256, 0, stream>>>(SL512b, pcl11b, SP256b,
                                                    I32(26), I32(27), pw_cc10, F32(49),
                                                    pw_cc11, F32(51), h1b, N, 512, 256);
    k_mfma_gemm<<<dim3(64, 8), 256, 0, stream>>>(h1b, nullptr, pw_c1o, F32(53),
                                                 nullptr, ab512a, 480, 1, 512, N, 1,
                                                 nullptr, nullptr, nullptr);
    k_mfma_gemm<<<dim3(64, 8), 256, 0, stream>>>(ab512a, nullptr, pw_c1o1, F32(55),
                                                 T512a, nullptr, 512, 1, 512, N, 0,
                                                 nullptr, nullptr, nullptr);
    k_slice_b<<<dim3(2048, 8), 256, 0, stream>>>(T512a, F32(14), I32(19), corr1b, N, 512, 512, 0);

    // --- Stage E: head ---
    k_mfma_gemm<<<dim3(64, 8), 256, 0, stream>>>(corr1b, nullptr, pw_s4, F32(57),
                                                 nullptr, ab512a, 512, 1, 512, N, 1,
                                                 nullptr, nullptr, nullptr);
    k_mfma_gemm<<<dim3(64, 4), 256, 0, stream>>>(ab512a, nullptr, pw_s2, F32(59),
                                                 T512a, nullptr, 512, 1, 256, N, 1,
                                                 nullptr, nullptr, nullptr);
    k_final<<<32, 256, 0, stream>>>(T512a, F32(60), F32(61), (float*)d_out, N);
}

// Round 17
// 671.729 us; speedup vs baseline: 1.3462x; 1.3462x over previous
//
#include <hip/hip_runtime.h>
#include <hip/hip_bf16.h>

#define HDIM 8192
#define FK 15

typedef __attribute__((ext_vector_type(8))) short bf16x8;
typedef __attribute__((ext_vector_type(8))) unsigned short u16x8;
typedef __attribute__((ext_vector_type(4))) float f32x4;

__device__ __forceinline__ void gload_lds16(const void* g, void* l) {
    __builtin_amdgcn_global_load_lds(
        (const __attribute__((address_space(1))) void*)g,
        (__attribute__((address_space(3))) void*)l, 16, 0, 0);
}

__device__ __forceinline__ float b2f(unsigned short s) {
    unsigned u = (unsigned)s << 16;
    float f;
    __builtin_memcpy(&f, &u, 4);
    return f;
}

// ---------------------------------------------------------------------------
// pack weights to bf16 in MFMA b-fragment order
__global__ void k_pack(const float* __restrict__ W, __hip_bfloat16* __restrict__ P,
                       int O, int C, int Cp, int Fk, int mode) {
    int e = blockIdx.x * 256 + threadIdx.x;
    int total = Fk * Cp * O;
    if (e >= total) return;
    int j = e & 7;
    int lane = (e >> 3) & 63;
    int tile = e >> 9;
    int OT = O >> 4;
    int ot = tile % OT, kt = tile / OT;
    int o = ot * 16 + (lane & 15);
    int kk = kt * 32 + (lane >> 4) * 8 + j;
    float v;
    if (mode == 1) {
        int f = kk / Cp, c = kk % Cp;
        v = (c < C) ? W[(size_t)o * C * Fk + (size_t)c * Fk + f] : 0.f;
    } else if (mode == 2) {
        int f = kk >> 5, oo = kk & 31;
        v = W[(size_t)o * 480 + oo * 15 + f];
    } else {
        v = W[(size_t)o * C + kk];
    }
    P[e] = __float2bfloat16(v);
}

// copy 4 el rows into bf16 catT cols 0..3 (z = stream)
__global__ void k_copy_el2(const float* __restrict__ el0, const float* __restrict__ el1,
                           __hip_bfloat16* __restrict__ c0, __hip_bfloat16* __restrict__ c1,
                           int N, int ld) {
    const float* el = blockIdx.z ? el1 : el0;
    __hip_bfloat16* catT = blockIdx.z ? c1 : c0;
    int n = blockIdx.x * 256 + threadIdx.x;
    if (n >= N) return;
#pragma unroll
    for (int j = 0; j < 4; ++j)
        catT[(size_t)n * ld + j] = __float2bfloat16(el[(size_t)j * N + n]);
}

// embed (z = stream): X (32,N) c-major -> bf16 outT[n*ld+coff+o] = lrelu(W@X+b)
__global__ __launch_bounds__(256) void k_embed2(const float* __restrict__ X0,
                                                const float* __restrict__ X1,
                                                const float* __restrict__ W,
                                                const float* __restrict__ b,
                                                __hip_bfloat16* __restrict__ o0,
                                                __hip_bfloat16* __restrict__ o1,
                                                int N, int O, int ld, int coff) {
    const float* X = blockIdx.z ? X1 : X0;
    __hip_bfloat16* outT = blockIdx.z ? o1 : o0;
    __shared__ float Xs[32][65];
    int tid = threadIdx.x;
    int n0 = blockIdx.x * 64;
    for (int e = tid; e < 32 * 64; e += 256) {
        int nn = e & 63, c = e >> 6;
        Xs[c][nn] = X[(size_t)c * N + n0 + nn];
    }
    __syncthreads();
    int ol = tid & 63, nl = tid >> 6;
    for (int o0i = 0; o0i < O; o0i += 64) {
        int o = o0i + ol;
        float wv[32];
#pragma unroll
        for (int c = 0; c < 32; ++c) wv[c] = W[o * 32 + c];
        float bv = b[o];
        for (int nn = nl; nn < 64; nn += 4) {
            float acc = bv;
#pragma unroll
            for (int c = 0; c < 32; ++c) acc += wv[c] * Xs[c][nn];
            acc = acc >= 0.f ? acc : 0.1f * acc;
            outT[(size_t)(n0 + nn) * ld + coff + o] = __float2bfloat16(acc);
        }
    }
}

// fp32 -> bf16 convert
__global__ void k_cvt(const float* __restrict__ in, __hip_bfloat16* __restrict__ out, int n) {
    int i = (blockIdx.x * 256 + threadIdx.x) * 4;
    if (i >= n) return;
    float4 v = *(const float4*)(in + i);
    out[i + 0] = __float2bfloat16(v.x);
    out[i + 1] = __float2bfloat16(v.y);
    out[i + 2] = __float2bfloat16(v.z);
    out[i + 3] = __float2bfloat16(v.w);
}

// ---------------------------------------------------------------------------
// Blur GEMM f3: block = 256h x (O/2), split-K halves,
// grid (H/256, 2, 4): y = O-panel, z = strm*2 + kh. 8 waves = OG x HG,
// wave = (MR*16)h x 64o. 3-slot LDS A ring (global_load_lds, XOR-pre-swizzled
// source), W direct-to-register depth-3, counted vmcnt(6) + one barrier/step.
struct W4 { bf16x8 r0, r1, r2, r3; };

template<int OG, int HG, int MR>
__global__ __launch_bounds__(512, 2) void k_blur_f3(
    const __hip_bfloat16* __restrict__ A0b, const __hip_bfloat16* __restrict__ A1b,
    const int* __restrict__ n0, const int* __restrict__ n1,
    const __hip_bfloat16* __restrict__ Wb, float* __restrict__ hbuf,
    int Cp, int O, int H) {
    __shared__ short abuf[3 * 8192];
    __shared__ int idx_s[8 * 256];
    int z = blockIdx.z;
    int strm = z >> 1, kh = z & 1;
    const unsigned short* A = (const unsigned short*)(strm ? A1b : A0b);
    const int* nbrs = strm ? n1 : n0;
    int CpT = Cp >> 5, OT = O >> 4;
    int fbeg = kh ? 8 : 0;
    int fcnt = kh ? (FK - 8) : 8;
    int S = fcnt * CpT;
    size_t NO = (size_t)H * O;
    float* outp = hbuf + (size_t)z * NO;
    const unsigned short* Wp = (const unsigned short*)Wb;
    int tid = threadIdx.x, lane = tid & 63, wid = tid >> 6;
    int r16 = lane & 15, g = lane >> 4;
    int og = wid % OG;
    int hg = wid / OG;
    int h0 = blockIdx.x * 256;
    int obase = blockIdx.y * (OG * 64);
    int otb = blockIdx.y * (OG * 4);
    int srw = lane >> 2;
    int sgseg = (lane & 3) ^ ((lane >> 3) & 3);
    int pseg = g ^ ((r16 >> 1) & 3);
    int hgbase = hg * (MR * 16);
    char* abase = (char*)abuf;

    for (int e = tid; e < fcnt * 256; e += 512)
        idx_s[e] = nbrs[(size_t)(fbeg + (e >> 8)) * H + h0 + (e & 255)];
    __syncthreads();

    f32x4 acc[MR][4];
#pragma unroll
    for (int m = 0; m < MR; ++m)
#pragma unroll
        for (int n = 0; n < 4; ++n) acc[m][n] = (f32x4){0.f, 0.f, 0.f, 0.f};

    W4 wA, wB, wC;
    int tS = 0, cS = 0, fS = 0;

#define STAGE_AW(SLOTA, W)                                                         \
    do {                                                                           \
        int gi0 = idx_s[fS * 256 + wid * 16 + srw];                                \
        int gi1 = idx_s[fS * 256 + (wid + 8) * 16 + srw];                          \
        gload_lds16(A + (size_t)gi0 * Cp + cS * 32 + sgseg * 8,                    \
                    abase + (SLOTA) * 16384 + wid * 1024);                         \
        gload_lds16(A + (size_t)gi1 * Cp + cS * 32 + sgseg * 8,                    \
                    abase + (SLOTA) * 16384 + (wid + 8) * 1024);                   \
        const unsigned short* wbp =                                                \
            Wp + ((size_t)(((fbeg + fS) * CpT + cS) * OT + otb + og * 4)) * 512 + lane * 8; \
        W.r0 = *(const bf16x8*)(wbp);                                              \
        W.r1 = *(const bf16x8*)(wbp + 512);                                        \
        W.r2 = *(const bf16x8*)(wbp + 1024);                                       \
        W.r3 = *(const bf16x8*)(wbp + 1536);                                       \
        if (tS < S - 1) { ++tS; if (++cS == CpT) { cS = 0; ++fS; } }               \
    } while (0)

#define FITER(SLOT, WCUR, WNXT)                                                    \
    do {                                                                           \
        __builtin_amdgcn_sched_barrier(0);                                         \
        asm volatile("s_waitcnt vmcnt(6)" ::: "memory");                           \
        __builtin_amdgcn_sched_barrier(0);                                         \
        __builtin_amdgcn_s_barrier();                                              \
        __builtin_amdgcn_sched_barrier(0);                                         \
        STAGE_AW(((SLOT) + 2) % 3, WNXT);                                          \
        const short* ab = abuf + (SLOT) * 8192;                                    \
        bf16x8 av[MR];                                                             \
        _Pragma("unroll")                                                          \
        for (int rb = 0; rb < MR; ++rb)                                            \
            av[rb] = *(const bf16x8*)(ab + (hgbase + rb * 16 + r16) * 32 + pseg * 8); \
        _Pragma("unroll")                                                          \
        for (int rb = 0; rb < MR; ++rb) {                                          \
            acc[rb][0] = __builtin_amdgcn_mfma_f32_16x16x32_bf16(av[rb], WCUR.r0, acc[rb][0], 0, 0, 0); \
            acc[rb][1] = __builtin_amdgcn_mfma_f32_16x16x32_bf16(av[rb], WCUR.r1, acc[rb][1], 0, 0, 0); \
            acc[rb][2] = __builtin_amdgcn_mfma_f32_16x16x32_bf16(av[rb], WCUR.r2, acc[rb][2], 0, 0, 0); \
            acc[rb][3] = __builtin_amdgcn_mfma_f32_16x16x32_bf16(av[rb], WCUR.r3, acc[rb][3], 0, 0, 0); \
        }                                                                          \
    } while (0)

    STAGE_AW(0, wA);
    STAGE_AW(1, wB);
    for (int t = 0; t < S; t += 3) {
        FITER(0, wA, wC);
        if (t + 1 < S) FITER(1, wB, wA);
        if (t + 2 < S) FITER(2, wC, wB);
    }
#undef FITER
#undef STAGE_AW

#pragma unroll
    for (int n = 0; n < 4; ++n) {
        int o = obase + og * 64 + n * 16 + r16;
#pragma unroll
        for (int m = 0; m < MR; ++m)
#pragma unroll
            for (int i = 0; i < 4; ++i)
                outp[(size_t)(h0 + hgbase + m * 16 + g * 4 + i) * O + o] = acc[m][n][i];
    }
}

// combine split-K halves (z = stream): out = lrelu(p0 + p1 + bias) -> bf16
__global__ void k_comb2(const float* __restrict__ p, const float* __restrict__ bias,
                        __hip_bfloat16* __restrict__ out0, __hip_bfloat16* __restrict__ out1,
                        int NO, int Om) {
    const float* pp = p + (size_t)blockIdx.z * 2 * NO;
    __hip_bfloat16* out = blockIdx.z ? out1 : out0;
    int i = blockIdx.x * 256 + threadIdx.x;
    int stride = gridDim.x * 256;
    for (; i < NO; i += stride) {
        float v = pp[i] + pp[i + NO] + bias[i & Om];
        v = v >= 0.f ? v : 0.1f * v;
        out[i] = __float2bfloat16(v);
    }
}

// ---------------------------------------------------------------------------
// R7 register-pipeline macros (dense bf16 GEMM)
#define DEF_PIPE_VARS                                                              \
    bf16x8 a00, a01, w00, w01, w02, w03;                                           \
    bf16x8 a10, a11, w10, w11, w12, w13;                                           \
    bf16x8 a20, a21, w20, w21, w22, w23;

#define LOADST(J, TEND, FEND)                                                      \
    do {                                                                           \
        const unsigned short* a0p = A + (size_t)i0c * Cp + cL * 32 + g * 8;        \
        const unsigned short* a1p = A + (size_t)i1c * Cp + cL * 32 + g * 8;        \
        a##J##0 = *(const bf16x8*)a0p;                                             \
        a##J##1 = *(const bf16x8*)a1p;                                             \
        const unsigned short* wbp = Wp + ((size_t)(tL * OT + otb)) * 512 + lane * 8; \
        w##J##0 = *(const bf16x8*)(wbp);                                           \
        w##J##1 = *(const bf16x8*)(wbp + 512);                                     \
        w##J##2 = *(const bf16x8*)(wbp + 1024);                                    \
        w##J##3 = *(const bf16x8*)(wbp + 1536);                                    \
        if (tL < (TEND) - 1) {                                                     \
            ++tL;                                                                  \
            if (++cL == CpT) {                                                     \
                cL = 0; ++fL;                                                      \
                i0c = i0n; i1c = i1n;                                              \
                if (fL + 1 < (FEND)) {                                             \
                    i0n = nbrs ? nbrs[(size_t)(fL + 1) * H + hrow] : hrow;         \
                    i1n = nbrs ? nbrs[(size_t)(fL + 1) * H + hrow + 16] : (hrow + 16); \
                }                                                                  \
            }                                                                      \
        }                                                                          \
    } while (0)

#define MFMAST(J)                                                                  \
    do {                                                                           \
        acc[0][0] = __builtin_amdgcn_mfma_f32_16x16x32_bf16(a##J##0, w##J##0, acc[0][0], 0, 0, 0); \
        acc[0][1] = __builtin_amdgcn_mfma_f32_16x16x32_bf16(a##J##0, w##J##1, acc[0][1], 0, 0, 0); \
        acc[0][2] = __builtin_amdgcn_mfma_f32_16x16x32_bf16(a##J##0, w##J##2, acc[0][2], 0, 0, 0); \
        acc[0][3] = __builtin_amdgcn_mfma_f32_16x16x32_bf16(a##J##0, w##J##3, acc[0][3], 0, 0, 0); \
        acc[1][0] = __builtin_amdgcn_mfma_f32_16x16x32_bf16(a##J##1, w##J##0, acc[1][0], 0, 0, 0); \
        acc[1][1] = __builtin_amdgcn_mfma_f32_16x16x32_bf16(a##J##1, w##J##1, acc[1][1], 0, 0, 0); \
        acc[1][2] = __builtin_amdgcn_mfma_f32_16x16x32_bf16(a##J##1, w##J##2, acc[1][2], 0, 0, 0); \
        acc[1][3] = __builtin_amdgcn_mfma_f32_16x16x32_bf16(a##J##1, w##J##3, acc[1][3], 0, 0, 0); \
    } while (0)

// MFMA GEMM (dense bf16 A), 128h x 64o tile, 4 waves.
__global__ __launch_bounds__(256) void k_mfma_gemm(const __hip_bfloat16* __restrict__ Ab,
                                                   const int* __restrict__ nbrs,
                                                   const __hip_bfloat16* __restrict__ Wb,
                                                   const float* __restrict__ bias,
                                                   float* __restrict__ outF,
                                                   __hip_bfloat16* __restrict__ outB,
                                                   int Cp, int Fk, int O, int H, int act,
                                                   const __hip_bfloat16* Ab1,
                                                   float* outF1, __hip_bfloat16* outB1) {
    if (blockIdx.z) { Ab = Ab1; outF = outF1; outB = outB1; }
    const unsigned short* A = (const unsigned short*)Ab;
    const unsigned short* Wp = (const unsigned short*)Wb;
    int tid = threadIdx.x, lane = tid & 63, w = tid >> 6;
    int r16 = lane & 15, g = lane >> 4;
    int h0 = blockIdx.x * 128, o0 = blockIdx.y * 64;
    int OT = O >> 4, CpT = Cp >> 5, S = Fk * CpT;
    int otb = o0 >> 4;
    int w32 = w * 32;
    int hrow = h0 + w32 + r16;

    int i0c = nbrs ? nbrs[hrow] : hrow;
    int i1c = nbrs ? nbrs[hrow + 16] : (hrow + 16);
    int i0n = i0c, i1n = i1c;
    if (Fk > 1) {
        i0n = nbrs[(size_t)H + hrow];
        i1n = nbrs[(size_t)H + hrow + 16];
    }

    f32x4 acc[2][4];
#pragma unroll
    for (int m = 0; m < 2; ++m)
#pragma unroll
        for (int n = 0; n < 4; ++n) acc[m][n] = (f32x4){0.f, 0.f, 0.f, 0.f};

    DEF_PIPE_VARS
    int tL = 0, cL = 0, fL = 0;

    LOADST(0, S, Fk);
    LOADST(1, S, Fk);
    for (int sb = 0; sb < S; sb += 3) {
        LOADST(2, S, Fk);
        MFMAST(0);
        LOADST(0, S, Fk);
        if (sb + 1 < S) MFMAST(1);
        LOADST(1, S, Fk);
        if (sb + 2 < S) MFMAST(2);
    }

#pragma unroll
    for (int n = 0; n < 4; ++n) {
        int o = o0 + n * 16 + r16;
        float bv = bias[o];
#pragma unroll
        for (int m = 0; m < 2; ++m) {
#pragma unroll
            for (int i = 0; i < 4; ++i) {
                int h = h0 + w32 + m * 16 + g * 4 + i;
                float v = acc[m][n][i] + bv;
                if (act) v = v >= 0.f ? v : 0.1f * v;
                if (outF) outF[(size_t)h * O + o] = v;
                if (outB) outB[(size_t)h * O + o] = __float2bfloat16(v);
            }
        }
    }
}

// ---------------------------------------------------------------------------
// slice (bf16 out)
__global__ void k_slice_b(const float* __restrict__ latT, const float* __restrict__ bary,
                          const int* __restrict__ off, __hip_bfloat16* __restrict__ outT,
                          int N, int C, int ld, int coff) {
    int cl = threadIdx.x & 63, rr = threadIdx.x >> 6;
    int n = blockIdx.x * 4 + rr;
    int c = blockIdx.y * 64 + cl;
    float s = 0.f;
#pragma unroll
    for (int j = 0; j < 4; ++j) {
        int o = off[(size_t)j * N + n];
        float w = bary[(size_t)j * N + n];
        s += latT[(size_t)o * C + c] * w;
    }
    outT[(size_t)n * ld + coff + c] = __float2bfloat16(s);
}

// fused slice -> splat (same bary/off pair): v = slice(latT)[n][c];
// dst[off_j][c] += v * bary_j  (dst pre-zeroed). Bit-identical to the
// previous slice-then-splat (value stays in register instead of HBM).
__global__ void k_slice_splat(const float* __restrict__ latT, const float* __restrict__ bary,
                              const int* __restrict__ off, float* __restrict__ dst,
                              int N, int C) {
    int cl = threadIdx.x & 63, rr = threadIdx.x >> 6;
    int n = blockIdx.x * 4 + rr;
    int c = blockIdx.y * 64 + cl;
    int o[4];
    float w[4];
    float s = 0.f;
#pragma unroll
    for (int j = 0; j < 4; ++j) {
        o[j] = off[(size_t)j * N + n];
        w[j] = bary[(size_t)j * N + n];
        s += latT[(size_t)o[j] * C + c] * w[j];
    }
#pragma unroll
    for (int j = 0; j < 4; ++j)
        atomicAdd(&dst[(size_t)o[j] * C + c], s * w[j]);
}

// ---------------------------------------------------------------------------
// MFMA correlation MLP. Block = 64 positions (same f), 4 waves.
// ALL gathered tables bf16 (L1, f2, P1).
__global__ __launch_bounds__(256) void k_corr_mfma(const __hip_bfloat16* __restrict__ L1b,
                                                   const __hip_bfloat16* __restrict__ f2b,
                                                   const __hip_bfloat16* __restrict__ P1b,
                                                   const int* __restrict__ idx1,
                                                   const int* __restrict__ idx2,
                                                   const __hip_bfloat16* __restrict__ W0p,
                                                   const float* __restrict__ b0,
                                                   const __hip_bfloat16* __restrict__ W1p,
                                                   const float* __restrict__ b1,
                                                   __hip_bfloat16* __restrict__ h1T,
                                                   int H, int C1, int C2) {
    __shared__ __hip_bfloat16 As[64 * 72];
    __shared__ __hip_bfloat16 A0s[64 * 40];
    __shared__ int i1s[64], i2s[64];
    const unsigned short* L1u = (const unsigned short*)L1b;
    const unsigned short* f2u = (const unsigned short*)f2b;
    const unsigned short* P1u = (const unsigned short*)P1b;
    int tid = threadIdx.x;
    int p0 = blockIdx.x * 64;
    int f = p0 >> 13;                 // H == 8192
    int h0 = p0 & (HDIM - 1);
    if (tid < 64) {
        i1s[tid] = idx1[(size_t)f * H + h0 + tid];
        i2s[tid] = idx2[(size_t)f * H + h0 + tid];
    }
    __syncthreads();
    int lane = tid & 63, wid = tid >> 6;
    int wh = wid * 16;
    int r16 = lane & 15, g = lane >> 4;
    int srow = tid >> 2, sseg = tid & 3;
    int K = C1 + C2;
    const unsigned short* W0u = (const unsigned short*)W0p;
    const unsigned short* W1u = (const unsigned short*)W1p;
    f32x4 acc[2];
    acc[0] = (f32x4){0.f, 0.f, 0.f, 0.f};
    acc[1] = (f32x4){0.f, 0.f, 0.f, 0.f};

    for (int c0 = 0; c0 < K; c0 += 64) {
        int cb = c0 + sseg * 16;
        float x[16];
        if (cb < C1) {
            u16x8 av0 = *(const u16x8*)(L1u + (size_t)i1s[srow] * C1 + cb);
            u16x8 av1 = *(const u16x8*)(L1u + (size_t)i1s[srow] * C1 + cb + 8);
            u16x8 bv0 = *(const u16x8*)(f2u + (size_t)i2s[srow] * C1 + cb);
            u16x8 bv1 = *(const u16x8*)(f2u + (size_t)i2s[srow] * C1 + cb + 8);
#pragma unroll
            for (int u = 0; u < 8; ++u) {
                x[u]     = b2f(av0[u]) * b2f(bv0[u]);
                x[8 + u] = b2f(av1[u]) * b2f(bv1[u]);
            }
        } else {
            u16x8 p0v = *(const u16x8*)(P1u + (size_t)i1s[srow] * C2 + (cb - C1));
            u16x8 p1v = *(const u16x8*)(P1u + (size_t)i1s[srow] * C2 + (cb - C1) + 8);
#pragma unroll
            for (int u = 0; u < 8; ++u) {
                x[u] = b2f(p0v[u]);
                x[8 + u] = b2f(p1v[u]);
            }
        }
        __syncthreads();
        __hip_bfloat16* dst = &As[srow * 72 + sseg * 16];
#pragma unroll
        for (int q = 0; q < 16; ++q) dst[q] = __float2bfloat16(x[q]);
        __syncthreads();
        int ktg = c0 >> 5;
#pragma unroll
        for (int kt = 0; kt < 2; ++kt) {
            bf16x8 a = *(const bf16x8*)(&As[(wh + r16) * 72 + kt * 32 + g * 8]);
            const unsigned short* wb = W0u + (size_t)((ktg + kt) * 2) * 512 + lane * 8;
            bf16x8 bf0 = *(const bf16x8*)(wb);
            bf16x8 bf1 = *(const bf16x8*)(wb + 512);
            acc[0] = __builtin_amdgcn_mfma_f32_16x16x32_bf16(a, bf0, acc[0], 0, 0, 0);
            acc[1] = __builtin_amdgcn_mfma_f32_16x16x32_bf16(a, bf1, acc[1], 0, 0, 0);
        }
    }
    __syncthreads();
#pragma unroll
    for (int ot = 0; ot < 2; ++ot) {
        int o = ot * 16 + r16;
        float bv = b0[o];
#pragma unroll
        for (int i = 0; i < 4; ++i) {
            int pr = wh + g * 4 + i;
            float v = acc[ot][i] + bv;
            v = v >= 0.f ? v : 0.1f * v;
            A0s[pr * 40 + o] = __float2bfloat16(v);
        }
    }
    __syncthreads();
    bf16x8 a1 = *(const bf16x8*)(&A0s[(wh + r16) * 40 + g * 8]);
    bf16x8 w1f0 = *(const bf16x8*)(W1u + lane * 8);
    bf16x8 w1f1 = *(const bf16x8*)(W1u + 512 + lane * 8);
    f32x4 acc1[2];
    acc1[0] = (f32x4){0.f, 0.f, 0.f, 0.f};
    acc1[1] = (f32x4){0.f, 0.f, 0.f, 0.f};
    acc1[0] = __builtin_amdgcn_mfma_f32_16x16x32_bf16(a1, w1f0, acc1[0], 0, 0, 0);
    acc1[1] = __builtin_amdgcn_mfma_f32_16x16x32_bf16(a1, w1f1, acc1[1], 0, 0, 0);
#pragma unroll
    for (int ot = 0; ot < 2; ++ot) {
        int o = ot * 16 + r16;
        float bv = b1[o];
#pragma unroll
        for (int i = 0; i < 4; ++i) {
            int h = h0 + wh + g * 4 + i;
            float v = acc1[ot][i] + bv;
            v = v >= 0.f ? v : 0.1f * v;
            h1T[(size_t)h * 480 + f * 32 + o] = __float2bfloat16(v);
        }
    }
}

// ---------------------------------------------------------------------------
// final 256 -> 3 head, writes (3, N) c-major
__global__ void k_final(const float* __restrict__ r2T, const float* __restrict__ W,
                        const float* __restrict__ b, float* __restrict__ out, int N) {
    int n = blockIdx.x * 256 + threadIdx.x;
    if (n >= N) return;
    float s0 = b[0], s1 = b[1], s2 = b[2];
    const float4* x4 = (const float4*)(r2T + (size_t)n * 256);
    for (int q = 0; q < 64; ++q) {
        float4 v = x4[q];
        float xs[4] = {v.x, v.y, v.z, v.w};
#pragma unroll
        for (int u = 0; u < 4; ++u) {
            int c = 4 * q + u;
            s0 = fmaf(W[c], xs[u], s0);
            s1 = fmaf(W[256 + c], xs[u], s1);
            s2 = fmaf(W[512 + c], xs[u], s2);
        }
    }
    out[n] = s0;
    out[(size_t)N + n] = s1;
    out[(size_t)2 * N + n] = s2;
}

// ---------------------------------------------------------------------------
extern "C" void kernel_launch(void* const* d_in, const int* in_sizes, int n_in,
                              void* d_out, int out_size, void* d_ws, size_t ws_size,
                              hipStream_t stream) {
    const int N = HDIM;
    auto F32 = [&](int i) { return (const float*)d_in[i]; };
    auto I32 = [&](int i) { return (const int*)d_in[i]; };

    char* base = (char*)d_ws;
    size_t off = 0;
    auto allocB = [&](size_t elems) -> __hip_bfloat16* {
        __hip_bfloat16* r = (__hip_bfloat16*)(base + off);
        off += ((elems * 2 + 255) / 256) * 256;
        return r;
    };
    auto allocF = [&](size_t elems) -> float* {
        float* r = (float*)(base + off);
        off += ((elems * 4 + 255) / 256) * 256;
        return r;
    };

    // packed bf16 weights
    __hip_bfloat16* pw_up2   = allocB((size_t)15 * 160 * 256);
    __hip_bfloat16* pw_up1   = allocB((size_t)15 * 544 * 512);
    __hip_bfloat16* pw_up2_1 = allocB((size_t)256 * 256);
    __hip_bfloat16* pw_up1_1 = allocB((size_t)512 * 512);
    __hip_bfloat16* pw_c2o   = allocB((size_t)480 * 256);
    __hip_bfloat16* pw_c2o1  = allocB((size_t)256 * 256);
    __hip_bfloat16* pw_c1o   = allocB((size_t)480 * 512);
    __hip_bfloat16* pw_c1o1  = allocB((size_t)512 * 512);
    __hip_bfloat16* pw_s4    = allocB((size_t)512 * 512);
    __hip_bfloat16* pw_s2    = allocB((size_t)512 * 256);
    __hip_bfloat16* pw_cc20  = allocB((size_t)256 * 32);
    __hip_bfloat16* pw_cc21  = allocB((size_t)32 * 32);
    __hip_bfloat16* pw_cc10  = allocB((size_t)768 * 32);
    __hip_bfloat16* pw_cc11  = allocB((size_t)32 * 32);
    // bf16 activations
    __hip_bfloat16* catb2a = allocB((size_t)N * 160);
    __hip_bfloat16* catb2b = allocB((size_t)N * 160);
    __hip_bfloat16* catb1a = allocB((size_t)N * 544);
    __hip_bfloat16* catb1b = allocB((size_t)N * 544);
    __hip_bfloat16* ab512a = allocB((size_t)N * 512);
    __hip_bfloat16* ab512b = allocB((size_t)N * 512);
    __hip_bfloat16* ab256a = allocB((size_t)N * 256);
    __hip_bfloat16* ab256b = allocB((size_t)N * 256);
    __hip_bfloat16* h1b    = allocB((size_t)N * 480);
    __hip_bfloat16* corr1b = allocB((size_t)N * 512);
    __hip_bfloat16* SL256b = allocB((size_t)N * 256);
    __hip_bfloat16* SL512b = allocB((size_t)N * 512);
    __hip_bfloat16* SP256b = allocB((size_t)N * 256);
    __hip_bfloat16* pclBb  = allocB((size_t)N * 256);   // corr2 f2 (bf16)
    __hip_bfloat16* pcl11b = allocB((size_t)N * 512);   // corr1 f2 (bf16)
    // fp32 buffers
    float* T512a  = allocF((size_t)N * 512);
    float* T512b  = allocF((size_t)N * 512);
    float* SL512  = allocF((size_t)N * 512);
    float* SL256  = allocF((size_t)N * 256);   // later SP256
    float* hbuf   = allocF((size_t)4 * N * 512);  // split-K partials (4 slabs)
    float* SP256 = SL256;
    (void)ws_size; (void)in_sizes; (void)n_in; (void)out_size;

    // --- weight packing (bf16, MFMA fragment order) ---
    auto pack = [&](const float* W, __hip_bfloat16* P, int O, int C, int Cp, int Fk, int mode) {
        int total = Fk * Cp * O;
        k_pack<<<(total + 255) / 256, 256, 0, stream>>>(W, P, O, C, Cp, Fk, mode);
    };
    pack(F32(32), pw_up2,   256, 132, 160, 15, 1);
    pack(F32(36), pw_up1,   512, 516, 544, 15, 1);
    pack(F32(34), pw_up2_1, 256, 256, 256, 1, 0);
    pack(F32(38), pw_up1_1, 512, 512, 512, 1, 0);
    pack(F32(44), pw_c2o,   256, 480, 480, 1, 2);
    pack(F32(46), pw_c2o1,  256, 256, 256, 1, 0);
    pack(F32(52), pw_c1o,   512, 480, 480, 1, 2);
    pack(F32(54), pw_c1o1,  512, 512, 512, 1, 0);
    pack(F32(56), pw_s4,    512, 512, 512, 1, 0);
    pack(F32(58), pw_s2,    256, 512, 512, 1, 0);
    pack(F32(40), pw_cc20,  32, 256, 256, 1, 0);
    pack(F32(42), pw_cc21,  32, 32, 32, 1, 0);
    pack(F32(48), pw_cc10,  32, 768, 768, 1, 0);
    pack(F32(50), pw_cc11,  32, 32, 32, 1, 0);

    // --- zero-init (pads + splat accumulators) ---
    hipMemsetAsync(catb2a, 0, (size_t)N * 160 * 2, stream);
    hipMemsetAsync(catb2b, 0, (size_t)N * 160 * 2, stream);
    hipMemsetAsync(catb1a, 0, (size_t)N * 544 * 2, stream);
    hipMemsetAsync(catb1b, 0, (size_t)N * 544 * 2, stream);
    hipMemsetAsync(SL256,  0, (size_t)N * 256 * 4, stream);
    hipMemsetAsync(SL512,  0, (size_t)N * 512 * 4, stream);

    // --- Stage A: level-2 embed + blur f3 + comb + conv + slices ---
    k_copy_el2<<<dim3(32, 1, 2), 256, 0, stream>>>(F32(6), F32(7), catb2a, catb2b, N, 160);
    k_embed2<<<dim3(128, 1, 2), 256, 0, stream>>>(F32(1), F32(4), F32(28), F32(29),
                                                  catb2a, catb2b, N, 128, 160, 4);
    k_blur_f3<2, 4, 4><<<dim3(32, 2, 4), 512, 0, stream>>>(catb2a, catb2b, I32(20), I32(21),
                                                           pw_up2, hbuf, 160, 256, N);
    k_comb2<<<dim3(2048, 1, 2), 256, 0, stream>>>(hbuf, F32(33), ab256a, ab256b, N * 256, 255);
    k_mfma_gemm<<<dim3(64, 4, 2), 256, 0, stream>>>(ab256a, nullptr, pw_up2_1, F32(35),
                                                    T512a, nullptr, 256, 1, 256, N, 0,
                                                    ab256b, T512b, nullptr);
    k_slice_b<<<dim3(2048, 4), 256, 0, stream>>>(T512a, F32(12), I32(17), catb1a, N, 256, 544, 4);
    k_slice_b<<<dim3(2048, 4), 256, 0, stream>>>(T512b, F32(11), I32(16), pclBb, N, 256, 256, 0);
    k_slice_b<<<dim3(2048, 4), 256, 0, stream>>>(T512b, F32(13), I32(18), catb1b, N, 256, 544, 4);

    // --- Stage B: corr2 (fused slice->splat) ---
    k_slice_splat<<<dim3(2048, 4), 256, 0, stream>>>(T512a, F32(10), I32(15), SL256, N, 256);
    k_cvt<<<(N * 256 / 4 + 255) / 256, 256, 0, stream>>>(SL256, SL256b, N * 256);
    k_corr_mfma<<<FK * HDIM / 64, 256, 0, stream>>>(SL256b, pclBb, (const __hip_bfloat16*)nullptr,
                                                    I32(24), I32(25), pw_cc20, F32(41),
                                                    pw_cc21, F32(43), h1b, N, 256, 0);
    k_mfma_gemm<<<dim3(64, 4), 256, 0, stream>>>(h1b, nullptr, pw_c2o, F32(45),
                                                 nullptr, ab256a, 480, 1, 256, N, 1,
                                                 nullptr, nullptr, nullptr);
    k_mfma_gemm<<<dim3(64, 4), 256, 0, stream>>>(ab256a, nullptr, pw_c2o1, F32(47),
                                                 T512a, nullptr, 256, 1, 256, N, 0,
                                                 nullptr, nullptr, nullptr);
    hipMemsetAsync(SP256, 0, (size_t)N * 256 * 4, stream);
    k_slice_splat<<<dim3(2048, 4), 256, 0, stream>>>(T512a, F32(12), I32(17), SP256, N, 256);
    k_cvt<<<(N * 256 / 4 + 255) / 256, 256, 0, stream>>>(SP256, SP256b, N * 256);

    // --- Stage C: level-1 embed + blur f3 + comb + conv + slices ---
    k_copy_el2<<<dim3(32, 1, 2), 256, 0, stream>>>(F32(8), F32(9), catb1a, catb1b, N, 544);
    k_embed2<<<dim3(128, 1, 2), 256, 0, stream>>>(F32(0), F32(3), F32(30), F32(31),
                                                  catb1a, catb1b, N, 256, 544, 260);
    k_blur_f3<4, 2, 8><<<dim3(32, 2, 4), 512, 0, stream>>>(catb1a, catb1b, I32(22), I32(23),
                                                           pw_up1, hbuf, 544, 512, N);
    k_comb2<<<dim3(2048, 1, 2), 256, 0, stream>>>(hbuf, F32(37), ab512a, ab512b, N * 512, 511);
    k_mfma_gemm<<<dim3(64, 8, 2), 256, 0, stream>>>(ab512a, nullptr, pw_up1_1, F32(39),
                                                    T512a, nullptr, 512, 1, 512, N, 0,
                                                    ab512b, T512b, nullptr);
    k_slice_b<<<dim3(2048, 8), 256, 0, stream>>>(T512b, F32(13), I32(18), pcl11b, N, 512, 512, 0);

    // --- Stage D: corr1 ---
    k_slice_splat<<<dim3(2048, 8), 256, 0, stream>>>(T512a, F32(12), I32(17), SL512, N, 512);
    k_cvt<<<(N * 512 / 4 + 255) / 256, 256, 0, stream>>>(SL512, SL512b, N * 512);
    k_corr_mfma<<<FK * HDIM / 64, 256, 0, stream>>>(SL512b, pcl11b, SP256b,
                                                    I32(26), I32(27), pw_cc10, F32(49),
                                                    pw_cc11, F32(51), h1b, N, 512, 256);
    k_mfma_gemm<<<dim3(64, 8), 256, 0, stream>>>(h1b, nullptr, pw_c1o, F32(53),
                                                 nullptr, ab512a, 480, 1, 512, N, 1,
                                                 nullptr, nullptr, nullptr);
    k_mfma_gemm<<<dim3(64, 8), 256, 0, stream>>>(ab512a, nullptr, pw_c1o1, F32(55),
                                                 T512a, nullptr, 512, 1, 512, N, 0,
                                                 nullptr, nullptr, nullptr);
    k_slice_b<<<dim3(2048, 8), 256, 0, stream>>>(T512a, F32(14), I32(19), corr1b, N, 512, 512, 0);

    // --- Stage E: head ---
    k_mfma_gemm<<<dim3(64, 8), 256, 0, stream>>>(corr1b, nullptr, pw_s4, F32(57),
                                                 nullptr, ab512a, 512, 1, 512, N, 1,
                                                 nullptr, nullptr, nullptr);
    k_mfma_gemm<<<dim3(64, 4), 256, 0, stream>>>(ab512a, nullptr, pw_s2, F32(59),
                                                 T512a, nullptr, 512, 1, 256, N, 1,
                                                 nullptr, nullptr, nullptr);
    k_final<<<32, 256, 0, stream>>>(T512a, F32(60), F32(61), (float*)d_out, N);
}